// Round 15
// baseline (305.262 us; speedup 1.0000x reference)
//
#include <hip/hip_runtime.h>
#include <cstdint>
#include <cstddef>

#define N_TOTAL 21760
#define BATCH   2
#define M_TOT   (BATCH * N_TOTAL)   // 43520
#define DMODEL  256
#define NHEAD   8
#define HDIM    32
#define FFN     1024

typedef __bf16 b16x8 __attribute__((ext_vector_type(8)));
typedef float  f32x4 __attribute__((ext_vector_type(4)));
typedef float  f32x2 __attribute__((ext_vector_type(2)));
typedef unsigned u32x4 __attribute__((ext_vector_type(4)));

typedef const __attribute__((address_space(1))) void g_void;
typedef __attribute__((address_space(3))) void lds_void;

#if defined(__has_builtin)
#if __has_builtin(__builtin_amdgcn_make_buffer_rsrc) && __has_builtin(__builtin_amdgcn_raw_buffer_load_b128)
#define MSDA_BUFLD 1
#endif
#endif

// fp32 -> bf16 RNE
__device__ __forceinline__ unsigned short f2b(float f) {
  union { float f; unsigned u; } v; v.f = f;
  unsigned r = v.u + 0x7FFF + ((v.u >> 16) & 1);
  return (unsigned short)(r >> 16);
}
__device__ __forceinline__ float b2f(unsigned short u) {
  union { unsigned u; float f; } v; v.u = (unsigned)u << 16;
  return v.f;
}

// bijective XCD de-swizzle (m204)
__device__ __forceinline__ int xcd_wgid(int bid, int nwg) {
  int q = nwg >> 3, r = nwg & 7;
  int xcd = bid & 7, k = bid >> 3;
  return (xcd < r ? xcd * (q + 1) : r * (q + 1) + (xcd - r) * q) + k;
}

// ---------------------------------------------- weight convert + transpose
// ranges: Wv [0,65536) Woff [65536,131072) Wattn [131072,163840)
//         Wo [163840,229376) W1 [229376,491520) W2 [491520,753664)
__global__ void wconv_all(const float* __restrict__ Wv, const float* __restrict__ Woff,
                          const float* __restrict__ Wattn, const float* __restrict__ Wo,
                          const float* __restrict__ W1, const float* __restrict__ W2,
                          unsigned short* __restrict__ dstbase) {
  int idx = blockIdx.x * 256 + threadIdx.x;  // 0 .. 753664
  const float* src; int K, N, off;
  if (idx < 65536)       { src = Wv;    K = 256;  N = 256;  off = 0;      }
  else if (idx < 131072) { src = Woff;  K = 256;  N = 256;  off = 65536;  idx -= 65536; }
  else if (idx < 163840) { src = Wattn; K = 256;  N = 128;  off = 131072; idx -= 131072; }
  else if (idx < 229376) { src = Wo;    K = 256;  N = 256;  off = 163840; idx -= 163840; }
  else if (idx < 491520) { src = W1;    K = 256;  N = 1024; off = 229376; idx -= 229376; }
  else if (idx < 753664) { src = W2;    K = 1024; N = 256;  off = 491520; idx -= 491520; }
  else return;
  int k = idx / N, n = idx - k * N;
  dstbase[off + (size_t)n * K + k] = f2b(src[idx]);
}

// ---------------------------------------------------------------- LayerNorm
__global__ void ln1_kernel(const float* __restrict__ x, const float* __restrict__ pos,
                           const float* __restrict__ w, const float* __restrict__ b,
                           unsigned short* __restrict__ vb, unsigned short* __restrict__ qb) {
  int t = threadIdx.x;
  int tkn = blockIdx.x * 4 + (t >> 6);
  int lane = t & 63;
  size_t base = (size_t)tkn * DMODEL + lane * 4;
  float4 xv = *(const float4*)&x[base];
  float s1 = xv.x + xv.y + xv.z + xv.w;
  float s2 = xv.x * xv.x + xv.y * xv.y + xv.z * xv.z + xv.w * xv.w;
  #pragma unroll
  for (int off = 32; off; off >>= 1) {
    s1 += __shfl_down(s1, off);
    s2 += __shfl_down(s2, off);
  }
  s1 = __shfl(s1, 0); s2 = __shfl(s2, 0);
  float m   = s1 * (1.0f / DMODEL);
  float var = s2 * (1.0f / DMODEL) - m * m;
  float rs  = rsqrtf(var + 1e-5f);
  float4 wv = *(const float4*)&w[lane * 4];
  float4 bv = *(const float4*)&b[lane * 4];
  float4 pv = *(const float4*)&pos[base];
  float o0 = (xv.x - m) * rs * wv.x + bv.x;
  float o1 = (xv.y - m) * rs * wv.y + bv.y;
  float o2 = (xv.z - m) * rs * wv.z + bv.z;
  float o3 = (xv.w - m) * rs * wv.w + bv.w;
  ushort4 vo = {f2b(o0), f2b(o1), f2b(o2), f2b(o3)};
  ushort4 qo = {f2b(o0 + pv.x), f2b(o1 + pv.y), f2b(o2 + pv.z), f2b(o3 + pv.w)};
  *(ushort4*)&vb[base] = vo;
  *(ushort4*)&qb[base] = qo;
}

// ------------------------------------------------------- bf16 MFMA GEMM core
// R10 structure (measured best): 1-phase m97 staging + T2 swizzle both-sides;
// bf16 output via LDS repack -> 256B stores. 32 KB LDS, 3 blocks/CU.
__device__ __forceinline__ void gemm_core(
    const unsigned short* __restrict__ A, const unsigned short* __restrict__ Bt,
    const float* __restrict__ bias,
    const float* __restrict__ addf, const unsigned short* __restrict__ addb,
    float* __restrict__ Cf, unsigned short* __restrict__ Cb,
    int K, int N, int relu, int row0, int col0,
    unsigned short* S /* 16384 shorts: As=S, Bs=S+8192 */) {
  unsigned short* As = S;
  unsigned short* Bs = S + 8192;
  int t  = threadIdx.x;
  int w  = t >> 6;
  int l  = t & 63;
  int wm = w >> 1, wn = w & 1;
  int lr = l & 15;
  int kq = l >> 4;

  f32x4 acc[4][4];
  #pragma unroll
  for (int i = 0; i < 4; ++i)
    #pragma unroll
    for (int j = 0; j < 4; ++j) acc[i][j] = (f32x4){0.f, 0.f, 0.f, 0.f};

  int srow = l >> 3;                      // row within 8-row chunk
  int swseg = ((l & 7) ^ srow) * 8;       // swizzled 16B granule (elements)

  for (int k0 = 0; k0 < K; k0 += 64) {
    #pragma unroll
    for (int i = 0; i < 4; ++i) {
      int c = w * 4 + i;
      const unsigned short* ga = A  + (size_t)(row0 + c * 8 + srow) * K + k0 + swseg;
      const unsigned short* gb = Bt + (size_t)(col0 + c * 8 + srow) * K + k0 + swseg;
      __builtin_amdgcn_global_load_lds((g_void*)ga, (lds_void*)(As + c * 512), 16, 0, 0);
      __builtin_amdgcn_global_load_lds((g_void*)gb, (lds_void*)(Bs + c * 512), 16, 0, 0);
    }
    __syncthreads();
    #pragma unroll
    for (int kk = 0; kk < 2; ++kk) {
      b16x8 aF[4], bF[4];
      #pragma unroll
      for (int i = 0; i < 4; ++i) {
        int row = wm * 64 + i * 16 + lr;
        int gp = (kk * 4 + kq) ^ (lr & 7);
        aF[i] = *(const b16x8*)&As[row * 64 + gp * 8];
      }
      #pragma unroll
      for (int j = 0; j < 4; ++j) {
        int row = wn * 64 + j * 16 + lr;
        int gp = (kk * 4 + kq) ^ (lr & 7);
        bF[j] = *(const b16x8*)&Bs[row * 64 + gp * 8];
      }
      #pragma unroll
      for (int i = 0; i < 4; ++i)
        #pragma unroll
        for (int j = 0; j < 4; ++j)
          acc[i][j] = __builtin_amdgcn_mfma_f32_16x16x32_bf16(aF[i], bF[j], acc[i][j], 0, 0, 0);
    }
    __syncthreads();
  }

  if (Cb) {
    // deposit into [128][128] repack buffer (col XOR'd by row&3 to spread banks)
    #pragma unroll
    for (int j = 0; j < 4; ++j) {
      int coll = wn * 64 + j * 16 + lr;
      int colg = col0 + coll;
      float bcol = bias[colg];
      #pragma unroll
      for (int i = 0; i < 4; ++i) {
        int rl0 = wm * 64 + i * 16 + kq * 4;
        #pragma unroll
        for (int r = 0; r < 4; ++r) {
          int rowl = rl0 + r;
          float o = acc[i][j][r] + bcol;
          if (relu) o = fmaxf(o, 0.0f);
          if (addf) o += addf[(size_t)(row0 + rowl) * N + colg];
          if (addb) o += b2f(addb[(size_t)(row0 + rowl) * N + colg]);
          S[rowl * 128 + (coll ^ ((rowl & 3) << 5))] = f2b(o);
        }
      }
    }
    __syncthreads();
    #pragma unroll
    for (int m = 0; m < 8; ++m) {
      int cc = m * 256 + t;
      int row = cc >> 4, g = cc & 15;
      float4 v = *(const float4*)&S[row * 128 + ((g ^ ((row & 3) << 2)) << 3)];
      *(float4*)&Cb[(size_t)(row0 + row) * N + col0 + g * 8] = v;
    }
  } else {
    #pragma unroll
    for (int j = 0; j < 4; ++j) {
      int colg = col0 + wn * 64 + j * 16 + lr;
      float bcol = bias[colg];
      #pragma unroll
      for (int i = 0; i < 4; ++i) {
        int r0g = row0 + wm * 64 + i * 16 + kq * 4;
        #pragma unroll
        for (int r = 0; r < 4; ++r) {
          int rowg = r0g + r;
          float o = acc[i][j][r] + bcol;
          if (relu) o = fmaxf(o, 0.0f);
          if (addf) o += addf[(size_t)rowg * N + colg];
          if (addb) o += b2f(addb[(size_t)rowg * N + colg]);
          Cf[(size_t)rowg * N + colg] = o;
        }
      }
    }
  }
}

// flat 1-D grid; XCD-chunked, column-tile fastest within a chunk
__global__ __launch_bounds__(256, 3)
void gemm_bf16(const unsigned short* __restrict__ A,
               const unsigned short* __restrict__ Bt,
               const float* __restrict__ bias,
               const float* __restrict__ addf, const unsigned short* __restrict__ addb,
               float* __restrict__ Cf, unsigned short* __restrict__ Cb,
               int K, int N, int relu, int ncolt) {
  __shared__ unsigned short S[16384];
  int wgid = xcd_wgid(blockIdx.x, gridDim.x);
  int row0 = (wgid / ncolt) * 128;
  int col0 = (wgid % ncolt) * 128;
  gemm_core(A, Bt, bias, addf, addb, Cf, Cb, K, N, relu, row0, col0, S);
}

// fused projections: sub-gemm y 0,1 -> value; 2,3 -> offsets; 4 -> attn logits
__global__ __launch_bounds__(256, 3)
void gemm_proj(const unsigned short* __restrict__ vb,
               const unsigned short* __restrict__ qb,
               const unsigned short* __restrict__ Wvt,
               const unsigned short* __restrict__ Wofft,
               const unsigned short* __restrict__ Wattnt,
               const float* __restrict__ bv, const float* __restrict__ boff,
               const float* __restrict__ battn,
               unsigned short* __restrict__ valb,
               unsigned short* __restrict__ offb,
               unsigned short* __restrict__ awb) {
  __shared__ unsigned short S[16384];
  int wgid = xcd_wgid(blockIdx.x, gridDim.x);
  int y = wgid % 5;              // y fastest -> A-panel reuse within XCD chunk
  int row0 = (wgid / 5) * 128;
  const unsigned short* A; const unsigned short* Bt; const float* bias;
  unsigned short* C; int col0, N;
  if (y < 2)      { A = vb; Bt = Wvt;    bias = bv;    C = valb; col0 = y * 128;       N = 256; }
  else if (y < 4) { A = qb; Bt = Wofft;  bias = boff;  C = offb; col0 = (y - 2) * 128; N = 256; }
  else            { A = qb; Bt = Wattnt; bias = battn; C = awb;  col0 = 0;             N = 128; }
  gemm_core(A, Bt, bias, nullptr, nullptr, nullptr, C, 256, N, 0, row0, col0, S);
}

// --------------------------------- Wo GEMM (128x256 tile) + fused LN2 epilogue
__global__ __launch_bounds__(512, 2)
void gemm_wo_ln2(const unsigned short* __restrict__ A,   // msdab
                 const unsigned short* __restrict__ Bt,  // Wot [256][256]
                 const float* __restrict__ bias,         // bo
                 const float* __restrict__ emb,          // embed fp32
                 const float* __restrict__ lnw, const float* __restrict__ lnb,
                 unsigned short* __restrict__ emb2b,
                 unsigned short* __restrict__ fb16) {
  __shared__ unsigned short S[24576];   // As 8192 + Bs 16384 (48 KB)
  __shared__ float lnS1[128 * 4], lnS2[128 * 4];
  __shared__ float lnM[128], lnR[128];
  unsigned short* As = S;
  unsigned short* Bs = S + 8192;
  int t  = threadIdx.x;
  int w  = t >> 6;
  int l  = t & 63;
  int wm = w >> 2, wn = w & 3;
  int lr = l & 15;
  int kq = l >> 4;
  int row0 = xcd_wgid(blockIdx.x, gridDim.x) * 128;

  f32x4 acc[4][4];
  #pragma unroll
  for (int i = 0; i < 4; ++i)
    #pragma unroll
    for (int j = 0; j < 4; ++j) acc[i][j] = (f32x4){0.f, 0.f, 0.f, 0.f};

  int srow = l >> 3;
  int swseg = ((l & 7) ^ srow) * 8;

  for (int k0 = 0; k0 < 256; k0 += 64) {
    #pragma unroll
    for (int i = 0; i < 2; ++i) {
      int c = w * 2 + i;
      const unsigned short* ga = A + (size_t)(row0 + c * 8 + srow) * 256 + k0 + swseg;
      __builtin_amdgcn_global_load_lds((g_void*)ga, (lds_void*)(As + c * 512), 16, 0, 0);
    }
    #pragma unroll
    for (int i = 0; i < 4; ++i) {
      int c = w * 4 + i;
      const unsigned short* gb = Bt + (size_t)(c * 8 + srow) * 256 + k0 + swseg;
      __builtin_amdgcn_global_load_lds((g_void*)gb, (lds_void*)(Bs + c * 512), 16, 0, 0);
    }
    __syncthreads();
    #pragma unroll
    for (int kk = 0; kk < 2; ++kk) {
      b16x8 aF[4], bF[4];
      #pragma unroll
      for (int i = 0; i < 4; ++i) {
        int row = wm * 64 + i * 16 + lr;
        int gp = (kk * 4 + kq) ^ (lr & 7);
        aF[i] = *(const b16x8*)&As[row * 64 + gp * 8];
      }
      #pragma unroll
      for (int j = 0; j < 4; ++j) {
        int row = wn * 64 + j * 16 + lr;
        int gp = (kk * 4 + kq) ^ (lr & 7);
        bF[j] = *(const b16x8*)&Bs[row * 64 + gp * 8];
      }
      #pragma unroll
      for (int i = 0; i < 4; ++i)
        #pragma unroll
        for (int j = 0; j < 4; ++j)
          acc[i][j] = __builtin_amdgcn_mfma_f32_16x16x32_bf16(aF[i], bF[j], acc[i][j], 0, 0, 0);
    }
    __syncthreads();
  }

  // pass 1: o = acc + bias + embed; partial row sums
  float s1[4][4] = {}, s2[4][4] = {};
  #pragma unroll
  for (int j = 0; j < 4; ++j) {
    int colg = wn * 64 + j * 16 + lr;
    float bcol = bias[colg];
    #pragma unroll
    for (int i = 0; i < 4; ++i) {
      int rowg = row0 + wm * 64 + i * 16 + kq * 4;
      #pragma unroll
      for (int r = 0; r < 4; ++r) {
        float o = acc[i][j][r] + bcol + emb[(size_t)(rowg + r) * 256 + colg];
        acc[i][j][r] = o;
        s1[i][r] += o;
        s2[i][r] += o * o;
      }
    }
  }
  #pragma unroll
  for (int m = 1; m < 16; m <<= 1) {
    #pragma unroll
    for (int i = 0; i < 4; ++i)
      #pragma unroll
      for (int r = 0; r < 4; ++r) {
        s1[i][r] += __shfl_xor(s1[i][r], m);
        s2[i][r] += __shfl_xor(s2[i][r], m);
      }
  }
  if (lr == 0) {
    #pragma unroll
    for (int i = 0; i < 4; ++i)
      #pragma unroll
      for (int r = 0; r < 4; ++r) {
        int rl = wm * 64 + i * 16 + kq * 4 + r;
        lnS1[rl * 4 + wn] = s1[i][r];
        lnS2[rl * 4 + wn] = s2[i][r];
      }
  }
  __syncthreads();
  if (t < 128) {
    float a = lnS1[t * 4] + lnS1[t * 4 + 1] + lnS1[t * 4 + 2] + lnS1[t * 4 + 3];
    float b = lnS2[t * 4] + lnS2[t * 4 + 1] + lnS2[t * 4 + 2] + lnS2[t * 4 + 3];
    float m = a * (1.0f / 256.0f);
    float var = b * (1.0f / 256.0f) - m * m;
    lnM[t] = m;
    lnR[t] = rsqrtf(var + 1e-5f);
  }
  __syncthreads();

  // repack passes: out 0 = emb2b (o), out 1 = fb16 (LN2(o)); halves of 128 cols
  #pragma unroll
  for (int outn = 0; outn < 2; ++outn) {
    unsigned short* dst = outn == 0 ? emb2b : fb16;
    #pragma unroll
    for (int half = 0; half < 2; ++half) {
      __syncthreads();
      if ((wn >> 1) == half) {
        #pragma unroll
        for (int j = 0; j < 4; ++j) {
          int colg = wn * 64 + j * 16 + lr;
          int coll = colg - half * 128;
          #pragma unroll
          for (int i = 0; i < 4; ++i) {
            #pragma unroll
            for (int r = 0; r < 4; ++r) {
              int rowl = wm * 64 + i * 16 + kq * 4 + r;
              float o = acc[i][j][r];
              float vv = outn == 0 ? o
                  : (o - lnM[rowl]) * lnR[rowl] * lnw[colg] + lnb[colg];
              S[rowl * 128 + (coll ^ ((rowl & 3) << 5))] = f2b(vv);
            }
          }
        }
      }
      __syncthreads();
      #pragma unroll
      for (int m = 0; m < 4; ++m) {
        int cc = m * 512 + t;
        int row = cc >> 4, g = cc & 15;
        float4 v = *(const float4*)&S[row * 128 + ((g ^ ((row & 3) << 2)) << 3)];
        *(float4*)&dst[(size_t)(row0 + row) * 256 + half * 128 + g * 8] = v;
      }
    }
  }
}

// --------------------------------------------------- MSDA sampling + softmax
// Phase 2 at 4x width: lane = (h, tap-group tg, dquad dq). dwordx4 gathers
// (8 bf16/iter), 8 iters; cross-tg reduce via 3 shfl_xor rounds.
__global__ void msda_kernel(const unsigned short* __restrict__ value,
                            const unsigned short* __restrict__ offb,
                            const unsigned short* __restrict__ awb,
                            const float* __restrict__ ref,
                            unsigned short* __restrict__ outb) {
  __shared__ int2 P[544];   // 8 heads * 68, half stride 34
  int bid = blockIdx.x;
  int tkn = (bid & 7) * (M_TOT / 8) + (bid >> 3);
  int t   = threadIdx.x;
  int b   = (tkn >= N_TOTAL) ? 1 : 0;

  if (t < 128) {
    int h = t >> 4, s = t & 15, lev = s >> 2, p = s & 3;
    float lg = b2f(awb[(size_t)tkn * 128 + h * 16 + s]);
    float mx = lg;
    #pragma unroll
    for (int m = 1; m < 16; m <<= 1) mx = fmaxf(mx, __shfl_xor(mx, m, 16));
    float e = __expf(lg - mx);
    float sum = e;
    #pragma unroll
    for (int m = 1; m < 16; m <<= 1) sum += __shfl_xor(sum, m, 16);
    float aw = e / sum;

    const int HL[4] = {128, 64, 32, 16};
    const int ST[4] = {0, 16384, 20480, 21504};
    int Wl = HL[lev];
    float rx = ref[(size_t)tkn * 8 + lev * 2 + 0];
    float ry = ref[(size_t)tkn * 8 + lev * 2 + 1];
    float ox = b2f(offb[(size_t)tkn * 256 + h * 32 + lev * 8 + p * 2 + 0]);
    float oy = b2f(offb[(size_t)tkn * 256 + h * 32 + lev * 8 + p * 2 + 1]);
    float x = rx * (float)Wl + ox - 0.5f;   // Hl == Wl all levels
    float y = ry * (float)Wl + oy - 0.5f;
    float x0f = floorf(x), y0f = floorf(y);
    float wx = x - x0f, wy = y - y0f;
    int x0 = (int)x0f, y0 = (int)y0f;
    float wt[4] = {(1.f - wx) * (1.f - wy), wx * (1.f - wy),
                   (1.f - wx) * wy, wx * wy};
    int base = b * N_TOTAL + ST[lev];
    #pragma unroll
    for (int tp = 0; tp < 4; ++tp) {
      int e4 = s * 4 + tp;                       // 0..63 within head
      int idx = h * 68 + (e4 >> 5) * 34 + (e4 & 31);
      int xi = x0 + (tp & 1), yi = y0 + (tp >> 1);
      bool ok = (xi >= 0) & (xi < Wl) & (yi >= 0) & (yi < Wl);
      float wgt = ok ? aw * wt[tp] : 0.f;
      int boff2 = ok ? (((base + yi * Wl + xi) * 256 + h * 32) * 2) : 0;
      P[idx] = (int2){__float_as_int(wgt), boff2};
    }
  }
  __syncthreads();

  int h  = t >> 5;          // 8 heads
  int g  = t & 31;
  int tg = g >> 2;          // 8 tap-groups (taps tg*8 .. tg*8+7)
  int dq = g & 3;           // 4 dquads (16B each)
  unsigned doff = dq * 16;
#ifdef MSDA_BUFLD
  __amdgpu_buffer_rsrc_t rsrc = __builtin_amdgcn_make_buffer_rsrc(
      (void*)value, (short)0, (int)(M_TOT * 512), 0x00020000);
#else
  const char* vbase = (const char*)value;
#endif
  f32x2 acc0 = {0.f, 0.f}, acc1 = {0.f, 0.f}, acc2 = {0.f, 0.f}, acc3 = {0.f, 0.f};
  #pragma unroll
  for (int it = 0; it < 8; ++it) {
    int j = tg * 8 + it;
    int2 pr = P[h * 68 + (j >> 5) * 34 + (j & 31)];
    float wgt = __int_as_float(pr.x);
    u32x4 v;
#ifdef MSDA_BUFLD
    v = (u32x4)__builtin_amdgcn_raw_buffer_load_b128(
        rsrc, (int)((unsigned)pr.y + doff), 0, 0);
#else
    v = *(const u32x4*)(vbase + (size_t)((unsigned)pr.y + doff));
#endif
    f32x2 w2 = {wgt, wgt};
    union { unsigned u; float f; } l0, h0, l1, h1, l2, h2, l3, h3;
    l0.u = v[0] << 16; h0.u = v[0];
    l1.u = v[1] << 16; h1.u = v[1];
    l2.u = v[2] << 16; h2.u = v[2];
    l3.u = v[3] << 16; h3.u = v[3];
    f32x2 v0 = {l0.f, h0.f}, v1 = {l1.f, h1.f}, v2 = {l2.f, h2.f}, v3 = {l3.f, h3.f};
    acc0 += w2 * v0;
    acc1 += w2 * v1;
    acc2 += w2 * v2;
    acc3 += w2 * v3;
  }
  // reduce over tg (t bits 2,3,4)
  #pragma unroll
  for (int m = 4; m <= 16; m <<= 1) {
    acc0.x += __shfl_xor(acc0.x, m); acc0.y += __shfl_xor(acc0.y, m);
    acc1.x += __shfl_xor(acc1.x, m); acc1.y += __shfl_xor(acc1.y, m);
    acc2.x += __shfl_xor(acc2.x, m); acc2.y += __shfl_xor(acc2.y, m);
    acc3.x += __shfl_xor(acc3.x, m); acc3.y += __shfl_xor(acc3.y, m);
  }
  if (tg == 0) {
    u32x4 pk;
    pk[0] = (unsigned)f2b(acc0.x) | ((unsigned)f2b(acc0.y) << 16);
    pk[1] = (unsigned)f2b(acc1.x) | ((unsigned)f2b(acc1.y) << 16);
    pk[2] = (unsigned)f2b(acc2.x) | ((unsigned)f2b(acc2.y) << 16);
    pk[3] = (unsigned)f2b(acc3.x) | ((unsigned)f2b(acc3.y) << 16);
    *(u32x4*)&outb[(size_t)tkn * 256 + h * 32 + dq * 8] = pk;
  }
}

// --------------------------------------------------------------- launcher
extern "C" void kernel_launch(void* const* d_in, const int* in_sizes, int n_in,
                              void* d_out, int out_size, void* d_ws, size_t ws_size,
                              hipStream_t stream) {
  const float* embed = (const float*)d_in[0];
  const float* pos   = (const float*)d_in[1];
  const float* refp  = (const float*)d_in[2];
  const float* ln1w  = (const float*)d_in[3];
  const float* ln1b  = (const float*)d_in[4];
  const float* ln2w  = (const float*)d_in[5];
  const float* ln2b  = (const float*)d_in[6];
  const float* Wv    = (const float*)d_in[7];
  const float* bv    = (const float*)d_in[8];
  const float* Woff  = (const float*)d_in[9];
  const float* boff  = (const float*)d_in[10];
  const float* Wattn = (const float*)d_in[11];
  const float* battn = (const float*)d_in[12];
  const float* Wo    = (const float*)d_in[13];
  const float* bo    = (const float*)d_in[14];
  const float* W1    = (const float*)d_in[15];
  const float* b1    = (const float*)d_in[16];
  const float* W2    = (const float*)d_in[17];
  const float* b2    = (const float*)d_in[18];
  float* out = (float*)d_out;
  float* ws  = (float*)d_ws;

  const size_t U = (size_t)M_TOT * DMODEL;  // 11,141,120 floats
  unsigned short* valb16 = (unsigned short*)ws;               // 0.5U floats
  unsigned short* offb16 = (unsigned short*)(ws + U / 2);     // 0.5U
  unsigned short* awb16  = (unsigned short*)(ws + U);         // 0.25U
  unsigned short* msdab  = (unsigned short*)(ws + U + U / 4); // 0.5U
  unsigned short* hid16  = (unsigned short*)ws;               // [0, 2U) after msda
  unsigned short* emb2b  = (unsigned short*)(ws + 2 * U);     // 0.5U bf16
  unsigned short* vb16   = (unsigned short*)(ws + 3 * U);         // 0.5U
  unsigned short* qb16   = (unsigned short*)(ws + 3 * U + U / 2); // 0.5U
  unsigned short* fb16   = (unsigned short*)(ws + 4 * U);         // 0.5U
  unsigned short* wbuf   = (unsigned short*)(ws + 4 * U + U / 2);

  unsigned short* Wvt    = wbuf;            // offsets match wconv_all
  unsigned short* Wofft  = wbuf + 65536;
  unsigned short* Wattnt = wbuf + 131072;
  unsigned short* Wot    = wbuf + 163840;
  unsigned short* W1t    = wbuf + 229376;
  unsigned short* W2t    = wbuf + 491520;

  wconv_all<<<(753664 + 255) / 256, 256, 0, stream>>>(Wv, Woff, Wattn, Wo, W1, W2, wbuf);

  ln1_kernel<<<M_TOT / 4, 256, 0, stream>>>(embed, pos, ln1w, ln1b, vb16, qb16);

  gemm_proj<<<(M_TOT / 128) * 5, 256, 0, stream>>>(
      vb16, qb16, Wvt, Wofft, Wattnt, bv, boff, battn, valb16, offb16, awb16);

  msda_kernel<<<M_TOT, 256, 0, stream>>>(valb16, offb16, awb16, refp, msdab);

  gemm_wo_ln2<<<M_TOT / 128, 512, 0, stream>>>(
      msdab, Wot, bo, embed, ln2w, ln2b, emb2b, fb16);

  gemm_bf16<<<(M_TOT / 128) * 8, 256, 0, stream>>>(
      fb16, W1t, b1, nullptr, nullptr, nullptr, hid16, 256, 1024, 1, 8);
  gemm_bf16<<<(M_TOT / 128) * 2, 256, 0, stream>>>(
      hid16, W2t, b2, nullptr, emb2b, out, nullptr, 1024, 256, 0, 2);
}

// Round 16
// 292.181 us; speedup vs baseline: 1.0448x; 1.0448x over previous
//
#include <hip/hip_runtime.h>
#include <cstdint>
#include <cstddef>

#define N_TOTAL 21760
#define BATCH   2
#define M_TOT   (BATCH * N_TOTAL)   // 43520
#define DMODEL  256
#define NHEAD   8
#define HDIM    32
#define FFN     1024

typedef __bf16 b16x8 __attribute__((ext_vector_type(8)));
typedef float  f32x4 __attribute__((ext_vector_type(4)));
typedef float  f32x2 __attribute__((ext_vector_type(2)));

typedef const __attribute__((address_space(1))) void g_void;
typedef __attribute__((address_space(3))) void lds_void;

#if defined(__has_builtin)
#if __has_builtin(__builtin_amdgcn_make_buffer_rsrc) && __has_builtin(__builtin_amdgcn_raw_buffer_load_b32)
#define MSDA_BUFLD 1
#endif
#endif

// fp32 -> bf16 RNE
__device__ __forceinline__ unsigned short f2b(float f) {
  union { float f; unsigned u; } v; v.f = f;
  unsigned r = v.u + 0x7FFF + ((v.u >> 16) & 1);
  return (unsigned short)(r >> 16);
}
__device__ __forceinline__ float b2f(unsigned short u) {
  union { unsigned u; float f; } v; v.u = (unsigned)u << 16;
  return v.f;
}

// bijective XCD de-swizzle (m204)
__device__ __forceinline__ int xcd_wgid(int bid, int nwg) {
  int q = nwg >> 3, r = nwg & 7;
  int xcd = bid & 7, k = bid >> 3;
  return (xcd < r ? xcd * (q + 1) : r * (q + 1) + (xcd - r) * q) + k;
}

// ---------------------------------------------- weight convert + transpose
// ranges: Wv [0,65536) Woff [65536,131072) Wattn [131072,163840)
//         Wo [163840,229376) W1 [229376,491520) W2 [491520,753664)
__global__ void wconv_all(const float* __restrict__ Wv, const float* __restrict__ Woff,
                          const float* __restrict__ Wattn, const float* __restrict__ Wo,
                          const float* __restrict__ W1, const float* __restrict__ W2,
                          unsigned short* __restrict__ dstbase) {
  int idx = blockIdx.x * 256 + threadIdx.x;  // 0 .. 753664
  const float* src; int K, N, off;
  if (idx < 65536)       { src = Wv;    K = 256;  N = 256;  off = 0;      }
  else if (idx < 131072) { src = Woff;  K = 256;  N = 256;  off = 65536;  idx -= 65536; }
  else if (idx < 163840) { src = Wattn; K = 256;  N = 128;  off = 131072; idx -= 131072; }
  else if (idx < 229376) { src = Wo;    K = 256;  N = 256;  off = 163840; idx -= 163840; }
  else if (idx < 491520) { src = W1;    K = 256;  N = 1024; off = 229376; idx -= 229376; }
  else if (idx < 753664) { src = W2;    K = 1024; N = 256;  off = 491520; idx -= 491520; }
  else return;
  int k = idx / N, n = idx - k * N;
  dstbase[off + (size_t)n * K + k] = f2b(src[idx]);
}

// ---------------------------------------------------------------- LayerNorm
// writes v (bf16), q = v + pos (bf16), and embed as bf16 (residual source)
__global__ void ln1_kernel(const float* __restrict__ x, const float* __restrict__ pos,
                           const float* __restrict__ w, const float* __restrict__ b,
                           unsigned short* __restrict__ vb, unsigned short* __restrict__ qb,
                           unsigned short* __restrict__ eb) {
  int t = threadIdx.x;
  int tkn = blockIdx.x * 4 + (t >> 6);
  int lane = t & 63;
  size_t base = (size_t)tkn * DMODEL + lane * 4;
  float4 xv = *(const float4*)&x[base];
  float s1 = xv.x + xv.y + xv.z + xv.w;
  float s2 = xv.x * xv.x + xv.y * xv.y + xv.z * xv.z + xv.w * xv.w;
  #pragma unroll
  for (int off = 32; off; off >>= 1) {
    s1 += __shfl_down(s1, off);
    s2 += __shfl_down(s2, off);
  }
  s1 = __shfl(s1, 0); s2 = __shfl(s2, 0);
  float m   = s1 * (1.0f / DMODEL);
  float var = s2 * (1.0f / DMODEL) - m * m;
  float rs  = rsqrtf(var + 1e-5f);
  float4 wv = *(const float4*)&w[lane * 4];
  float4 bv = *(const float4*)&b[lane * 4];
  float4 pv = *(const float4*)&pos[base];
  float o0 = (xv.x - m) * rs * wv.x + bv.x;
  float o1 = (xv.y - m) * rs * wv.y + bv.y;
  float o2 = (xv.z - m) * rs * wv.z + bv.z;
  float o3 = (xv.w - m) * rs * wv.w + bv.w;
  ushort4 vo = {f2b(o0), f2b(o1), f2b(o2), f2b(o3)};
  ushort4 qo = {f2b(o0 + pv.x), f2b(o1 + pv.y), f2b(o2 + pv.z), f2b(o3 + pv.w)};
  ushort4 eo = {f2b(xv.x), f2b(xv.y), f2b(xv.z), f2b(xv.w)};
  *(ushort4*)&vb[base] = vo;
  *(ushort4*)&qb[base] = qo;
  *(ushort4*)&eb[base] = eo;
}

// ------------------------------------------------------- bf16 MFMA GEMM core
// R10 structure (measured best): 1-phase m97 staging + T2 swizzle both-sides;
// bf16 output via LDS repack -> 256B stores. 32 KB LDS, 3 blocks/CU.
__device__ __forceinline__ void gemm_core(
    const unsigned short* __restrict__ A, const unsigned short* __restrict__ Bt,
    const float* __restrict__ bias,
    const float* __restrict__ addf, const unsigned short* __restrict__ addb,
    float* __restrict__ Cf, unsigned short* __restrict__ Cb,
    int K, int N, int relu, int row0, int col0,
    unsigned short* S /* 16384 shorts: As=S, Bs=S+8192 */) {
  unsigned short* As = S;
  unsigned short* Bs = S + 8192;
  int t  = threadIdx.x;
  int w  = t >> 6;
  int l  = t & 63;
  int wm = w >> 1, wn = w & 1;
  int lr = l & 15;
  int kq = l >> 4;

  f32x4 acc[4][4];
  #pragma unroll
  for (int i = 0; i < 4; ++i)
    #pragma unroll
    for (int j = 0; j < 4; ++j) acc[i][j] = (f32x4){0.f, 0.f, 0.f, 0.f};

  int srow = l >> 3;                      // row within 8-row chunk
  int swseg = ((l & 7) ^ srow) * 8;       // swizzled 16B granule (elements)

  for (int k0 = 0; k0 < K; k0 += 64) {
    #pragma unroll
    for (int i = 0; i < 4; ++i) {
      int c = w * 4 + i;
      const unsigned short* ga = A  + (size_t)(row0 + c * 8 + srow) * K + k0 + swseg;
      const unsigned short* gb = Bt + (size_t)(col0 + c * 8 + srow) * K + k0 + swseg;
      __builtin_amdgcn_global_load_lds((g_void*)ga, (lds_void*)(As + c * 512), 16, 0, 0);
      __builtin_amdgcn_global_load_lds((g_void*)gb, (lds_void*)(Bs + c * 512), 16, 0, 0);
    }
    __syncthreads();
    #pragma unroll
    for (int kk = 0; kk < 2; ++kk) {
      b16x8 aF[4], bF[4];
      #pragma unroll
      for (int i = 0; i < 4; ++i) {
        int row = wm * 64 + i * 16 + lr;
        int gp = (kk * 4 + kq) ^ (lr & 7);
        aF[i] = *(const b16x8*)&As[row * 64 + gp * 8];
      }
      #pragma unroll
      for (int j = 0; j < 4; ++j) {
        int row = wn * 64 + j * 16 + lr;
        int gp = (kk * 4 + kq) ^ (lr & 7);
        bF[j] = *(const b16x8*)&Bs[row * 64 + gp * 8];
      }
      #pragma unroll
      for (int i = 0; i < 4; ++i)
        #pragma unroll
        for (int j = 0; j < 4; ++j)
          acc[i][j] = __builtin_amdgcn_mfma_f32_16x16x32_bf16(aF[i], bF[j], acc[i][j], 0, 0, 0);
    }
    __syncthreads();
  }

  if (Cb) {
    // deposit into [128][128] repack buffer (col XOR'd by row&3 to spread banks)
    #pragma unroll
    for (int j = 0; j < 4; ++j) {
      int coll = wn * 64 + j * 16 + lr;
      int colg = col0 + coll;
      float bcol = bias[colg];
      #pragma unroll
      for (int i = 0; i < 4; ++i) {
        int rl0 = wm * 64 + i * 16 + kq * 4;
        #pragma unroll
        for (int r = 0; r < 4; ++r) {
          int rowl = rl0 + r;
          float o = acc[i][j][r] + bcol;
          if (relu) o = fmaxf(o, 0.0f);
          if (addf) o += addf[(size_t)(row0 + rowl) * N + colg];
          if (addb) o += b2f(addb[(size_t)(row0 + rowl) * N + colg]);
          S[rowl * 128 + (coll ^ ((rowl & 3) << 5))] = f2b(o);
        }
      }
    }
    __syncthreads();
    #pragma unroll
    for (int m = 0; m < 8; ++m) {
      int cc = m * 256 + t;
      int row = cc >> 4, g = cc & 15;
      float4 v = *(const float4*)&S[row * 128 + ((g ^ ((row & 3) << 2)) << 3)];
      *(float4*)&Cb[(size_t)(row0 + row) * N + col0 + g * 8] = v;
    }
  } else {
    #pragma unroll
    for (int j = 0; j < 4; ++j) {
      int colg = col0 + wn * 64 + j * 16 + lr;
      float bcol = bias[colg];
      #pragma unroll
      for (int i = 0; i < 4; ++i) {
        int r0g = row0 + wm * 64 + i * 16 + kq * 4;
        #pragma unroll
        for (int r = 0; r < 4; ++r) {
          int rowg = r0g + r;
          float o = acc[i][j][r] + bcol;
          if (relu) o = fmaxf(o, 0.0f);
          if (addf) o += addf[(size_t)rowg * N + colg];
          if (addb) o += b2f(addb[(size_t)rowg * N + colg]);
          Cf[(size_t)rowg * N + colg] = o;
        }
      }
    }
  }
}

// flat 1-D grid; XCD-chunked, column-tile fastest within a chunk
__global__ __launch_bounds__(256, 3)
void gemm_bf16(const unsigned short* __restrict__ A,
               const unsigned short* __restrict__ Bt,
               const float* __restrict__ bias,
               const float* __restrict__ addf, const unsigned short* __restrict__ addb,
               float* __restrict__ Cf, unsigned short* __restrict__ Cb,
               int K, int N, int relu, int ncolt) {
  __shared__ unsigned short S[16384];
  int wgid = xcd_wgid(blockIdx.x, gridDim.x);
  int row0 = (wgid / ncolt) * 128;
  int col0 = (wgid % ncolt) * 128;
  gemm_core(A, Bt, bias, addf, addb, Cf, Cb, K, N, relu, row0, col0, S);
}

// fused projections: sub-gemm y 0,1 -> value; 2,3 -> offsets; 4 -> attn logits
__global__ __launch_bounds__(256, 3)
void gemm_proj(const unsigned short* __restrict__ vb,
               const unsigned short* __restrict__ qb,
               const unsigned short* __restrict__ Wvt,
               const unsigned short* __restrict__ Wofft,
               const unsigned short* __restrict__ Wattnt,
               const float* __restrict__ bv, const float* __restrict__ boff,
               const float* __restrict__ battn,
               unsigned short* __restrict__ valb,
               unsigned short* __restrict__ offb,
               unsigned short* __restrict__ awb) {
  __shared__ unsigned short S[16384];
  int wgid = xcd_wgid(blockIdx.x, gridDim.x);
  int y = wgid % 5;              // y fastest -> A-panel reuse within XCD chunk
  int row0 = (wgid / 5) * 128;
  const unsigned short* A; const unsigned short* Bt; const float* bias;
  unsigned short* C; int col0, N;
  if (y < 2)      { A = vb; Bt = Wvt;    bias = bv;    C = valb; col0 = y * 128;       N = 256; }
  else if (y < 4) { A = qb; Bt = Wofft;  bias = boff;  C = offb; col0 = (y - 2) * 128; N = 256; }
  else            { A = qb; Bt = Wattnt; bias = battn; C = awb;  col0 = 0;             N = 128; }
  gemm_core(A, Bt, bias, nullptr, nullptr, nullptr, C, 256, N, 0, row0, col0, S);
}

// --------------------------------- Wo GEMM (128x256 tile) + fused LN2 epilogue
// residual read from bf16 emb16 (saves 44.6 MB fp32 read vs fp32 embed)
__global__ __launch_bounds__(512, 2)
void gemm_wo_ln2(const unsigned short* __restrict__ A,    // msdab
                 const unsigned short* __restrict__ Bt,   // Wot [256][256]
                 const float* __restrict__ bias,          // bo
                 const unsigned short* __restrict__ emb,  // embed bf16
                 const float* __restrict__ lnw, const float* __restrict__ lnb,
                 unsigned short* __restrict__ emb2b,
                 unsigned short* __restrict__ fb16) {
  __shared__ unsigned short S[24576];   // As 8192 + Bs 16384 (48 KB)
  __shared__ float lnS1[128 * 4], lnS2[128 * 4];
  __shared__ float lnM[128], lnR[128];
  unsigned short* As = S;
  unsigned short* Bs = S + 8192;
  int t  = threadIdx.x;
  int w  = t >> 6;
  int l  = t & 63;
  int wm = w >> 2, wn = w & 3;
  int lr = l & 15;
  int kq = l >> 4;
  int row0 = xcd_wgid(blockIdx.x, gridDim.x) * 128;

  f32x4 acc[4][4];
  #pragma unroll
  for (int i = 0; i < 4; ++i)
    #pragma unroll
    for (int j = 0; j < 4; ++j) acc[i][j] = (f32x4){0.f, 0.f, 0.f, 0.f};

  int srow = l >> 3;
  int swseg = ((l & 7) ^ srow) * 8;

  for (int k0 = 0; k0 < 256; k0 += 64) {
    #pragma unroll
    for (int i = 0; i < 2; ++i) {
      int c = w * 2 + i;
      const unsigned short* ga = A + (size_t)(row0 + c * 8 + srow) * 256 + k0 + swseg;
      __builtin_amdgcn_global_load_lds((g_void*)ga, (lds_void*)(As + c * 512), 16, 0, 0);
    }
    #pragma unroll
    for (int i = 0; i < 4; ++i) {
      int c = w * 4 + i;
      const unsigned short* gb = Bt + (size_t)(c * 8 + srow) * 256 + k0 + swseg;
      __builtin_amdgcn_global_load_lds((g_void*)gb, (lds_void*)(Bs + c * 512), 16, 0, 0);
    }
    __syncthreads();
    #pragma unroll
    for (int kk = 0; kk < 2; ++kk) {
      b16x8 aF[4], bF[4];
      #pragma unroll
      for (int i = 0; i < 4; ++i) {
        int row = wm * 64 + i * 16 + lr;
        int gp = (kk * 4 + kq) ^ (lr & 7);
        aF[i] = *(const b16x8*)&As[row * 64 + gp * 8];
      }
      #pragma unroll
      for (int j = 0; j < 4; ++j) {
        int row = wn * 64 + j * 16 + lr;
        int gp = (kk * 4 + kq) ^ (lr & 7);
        bF[j] = *(const b16x8*)&Bs[row * 64 + gp * 8];
      }
      #pragma unroll
      for (int i = 0; i < 4; ++i)
        #pragma unroll
        for (int j = 0; j < 4; ++j)
          acc[i][j] = __builtin_amdgcn_mfma_f32_16x16x32_bf16(aF[i], bF[j], acc[i][j], 0, 0, 0);
    }
    __syncthreads();
  }

  // pass 1: o = acc + bias + embed; partial row sums
  float s1[4][4] = {}, s2[4][4] = {};
  #pragma unroll
  for (int j = 0; j < 4; ++j) {
    int colg = wn * 64 + j * 16 + lr;
    float bcol = bias[colg];
    #pragma unroll
    for (int i = 0; i < 4; ++i) {
      int rowg = row0 + wm * 64 + i * 16 + kq * 4;
      #pragma unroll
      for (int r = 0; r < 4; ++r) {
        float o = acc[i][j][r] + bcol + b2f(emb[(size_t)(rowg + r) * 256 + colg]);
        acc[i][j][r] = o;
        s1[i][r] += o;
        s2[i][r] += o * o;
      }
    }
  }
  #pragma unroll
  for (int m = 1; m < 16; m <<= 1) {
    #pragma unroll
    for (int i = 0; i < 4; ++i)
      #pragma unroll
      for (int r = 0; r < 4; ++r) {
        s1[i][r] += __shfl_xor(s1[i][r], m);
        s2[i][r] += __shfl_xor(s2[i][r], m);
      }
  }
  if (lr == 0) {
    #pragma unroll
    for (int i = 0; i < 4; ++i)
      #pragma unroll
      for (int r = 0; r < 4; ++r) {
        int rl = wm * 64 + i * 16 + kq * 4 + r;
        lnS1[rl * 4 + wn] = s1[i][r];
        lnS2[rl * 4 + wn] = s2[i][r];
      }
  }
  __syncthreads();
  if (t < 128) {
    float a = lnS1[t * 4] + lnS1[t * 4 + 1] + lnS1[t * 4 + 2] + lnS1[t * 4 + 3];
    float b = lnS2[t * 4] + lnS2[t * 4 + 1] + lnS2[t * 4 + 2] + lnS2[t * 4 + 3];
    float m = a * (1.0f / 256.0f);
    float var = b * (1.0f / 256.0f) - m * m;
    lnM[t] = m;
    lnR[t] = rsqrtf(var + 1e-5f);
  }
  __syncthreads();

  // repack passes: out 0 = emb2b (o), out 1 = fb16 (LN2(o)); halves of 128 cols
  #pragma unroll
  for (int outn = 0; outn < 2; ++outn) {
    unsigned short* dst = outn == 0 ? emb2b : fb16;
    #pragma unroll
    for (int half = 0; half < 2; ++half) {
      __syncthreads();
      if ((wn >> 1) == half) {
        #pragma unroll
        for (int j = 0; j < 4; ++j) {
          int colg = wn * 64 + j * 16 + lr;
          int coll = colg - half * 128;
          #pragma unroll
          for (int i = 0; i < 4; ++i) {
            #pragma unroll
            for (int r = 0; r < 4; ++r) {
              int rowl = wm * 64 + i * 16 + kq * 4 + r;
              float o = acc[i][j][r];
              float vv = outn == 0 ? o
                  : (o - lnM[rowl]) * lnR[rowl] * lnw[colg] + lnb[colg];
              S[rowl * 128 + (coll ^ ((rowl & 3) << 5))] = f2b(vv);
            }
          }
        }
      }
      __syncthreads();
      #pragma unroll
      for (int m = 0; m < 4; ++m) {
        int cc = m * 512 + t;
        int row = cc >> 4, g = cc & 15;
        float4 v = *(const float4*)&S[row * 128 + ((g ^ ((row & 3) << 2)) << 3)];
        *(float4*)&dst[(size_t)(row0 + row) * 256 + half * 128 + g * 8] = v;
      }
    }
  }
}

// --------------------------------------------------- MSDA sampling + softmax
// R13-exact phase 2 (measured best): single int2 P read, buffer load, pk_fma.
__global__ void msda_kernel(const unsigned short* __restrict__ value,
                            const unsigned short* __restrict__ offb,
                            const unsigned short* __restrict__ awb,
                            const float* __restrict__ ref,
                            unsigned short* __restrict__ outb) {
  __shared__ int2 P[544];   // 8 heads * 68, half stride 34
  int bid = blockIdx.x;
  int tkn = (bid & 7) * (M_TOT / 8) + (bid >> 3);
  int t   = threadIdx.x;
  int b   = (tkn >= N_TOTAL) ? 1 : 0;

  if (t < 128) {
    int h = t >> 4, s = t & 15, lev = s >> 2, p = s & 3;
    float lg = b2f(awb[(size_t)tkn * 128 + h * 16 + s]);
    float mx = lg;
    #pragma unroll
    for (int m = 1; m < 16; m <<= 1) mx = fmaxf(mx, __shfl_xor(mx, m, 16));
    float e = __expf(lg - mx);
    float sum = e;
    #pragma unroll
    for (int m = 1; m < 16; m <<= 1) sum += __shfl_xor(sum, m, 16);
    float aw = e / sum;

    const int HL[4] = {128, 64, 32, 16};
    const int ST[4] = {0, 16384, 20480, 21504};
    int Wl = HL[lev];
    float rx = ref[(size_t)tkn * 8 + lev * 2 + 0];
    float ry = ref[(size_t)tkn * 8 + lev * 2 + 1];
    float ox = b2f(offb[(size_t)tkn * 256 + h * 32 + lev * 8 + p * 2 + 0]);
    float oy = b2f(offb[(size_t)tkn * 256 + h * 32 + lev * 8 + p * 2 + 1]);
    float x = rx * (float)Wl + ox - 0.5f;   // Hl == Wl all levels
    float y = ry * (float)Wl + oy - 0.5f;
    float x0f = floorf(x), y0f = floorf(y);
    float wx = x - x0f, wy = y - y0f;
    int x0 = (int)x0f, y0 = (int)y0f;
    float wt[4] = {(1.f - wx) * (1.f - wy), wx * (1.f - wy),
                   (1.f - wx) * wy, wx * wy};
    int base = b * N_TOTAL + ST[lev];
    #pragma unroll
    for (int tp = 0; tp < 4; ++tp) {
      int e4 = s * 4 + tp;                       // 0..63 within head
      int idx = h * 68 + (e4 >> 5) * 34 + (e4 & 31);
      int xi = x0 + (tp & 1), yi = y0 + (tp >> 1);
      bool ok = (xi >= 0) & (xi < Wl) & (yi >= 0) & (yi < Wl);
      float wgt = ok ? aw * wt[tp] : 0.f;
      int boff2 = ok ? (((base + yi * Wl + xi) * 256 + h * 32) * 2) : 0;
      P[idx] = (int2){__float_as_int(wgt), boff2};
    }
  }
  __syncthreads();

  int h = t >> 5, g = t & 31, dp = g & 15, half = g >> 4;
  int o = h * 68 + half * 34;
  unsigned doff = dp * 4;  // byte offset of d-pair within 64B head segment
#ifdef MSDA_BUFLD
  __amdgpu_buffer_rsrc_t rsrc = __builtin_amdgcn_make_buffer_rsrc(
      (void*)value, (short)0, (int)(M_TOT * 512), 0x00020000);
#else
  const char* vbase = (const char*)value;
#endif
  f32x2 acc = {0.f, 0.f};
  #pragma unroll 16
  for (int j = 0; j < 32; ++j) {
    int2 pr = P[o + j];
    float wgt = __int_as_float(pr.x);
#ifdef MSDA_BUFLD
    unsigned v = __builtin_amdgcn_raw_buffer_load_b32(
        rsrc, (int)((unsigned)pr.y + doff), 0, 0);
#else
    unsigned v = *(const unsigned*)(vbase + (size_t)((unsigned)pr.y + doff));
#endif
    union { unsigned u; float f; } lo, hi;
    lo.u = v << 16;
    hi.u = v;                         // junk low mantissa: < 1 bf16 ulp
    f32x2 vv = {lo.f, hi.f};
    f32x2 w2 = {wgt, wgt};
    acc += w2 * vv;                   // v_pk_fma_f32
  }
  acc.x += __shfl_xor(acc.x, 16);
  acc.y += __shfl_xor(acc.y, 16);
  if (half == 0) {
    unsigned pk = (unsigned)f2b(acc.x) | ((unsigned)f2b(acc.y) << 16);
    *(unsigned*)&outb[(size_t)tkn * 256 + h * 32 + dp * 2] = pk;
  }
}

// --------------------------------------------------------------- launcher
extern "C" void kernel_launch(void* const* d_in, const int* in_sizes, int n_in,
                              void* d_out, int out_size, void* d_ws, size_t ws_size,
                              hipStream_t stream) {
  const float* embed = (const float*)d_in[0];
  const float* pos   = (const float*)d_in[1];
  const float* refp  = (const float*)d_in[2];
  const float* ln1w  = (const float*)d_in[3];
  const float* ln1b  = (const float*)d_in[4];
  const float* ln2w  = (const float*)d_in[5];
  const float* ln2b  = (const float*)d_in[6];
  const float* Wv    = (const float*)d_in[7];
  const float* bv    = (const float*)d_in[8];
  const float* Woff  = (const float*)d_in[9];
  const float* boff  = (const float*)d_in[10];
  const float* Wattn = (const float*)d_in[11];
  const float* battn = (const float*)d_in[12];
  const float* Wo    = (const float*)d_in[13];
  const float* bo    = (const float*)d_in[14];
  const float* W1    = (const float*)d_in[15];
  const float* b1    = (const float*)d_in[16];
  const float* W2    = (const float*)d_in[17];
  const float* b2    = (const float*)d_in[18];
  float* out = (float*)d_out;
  float* ws  = (float*)d_ws;

  const size_t U = (size_t)M_TOT * DMODEL;  // 11,141,120 floats
  unsigned short* valb16 = (unsigned short*)ws;               // 0.5U floats
  unsigned short* offb16 = (unsigned short*)(ws + U / 2);     // 0.5U
  unsigned short* awb16  = (unsigned short*)(ws + U);         // 0.25U
  unsigned short* msdab  = (unsigned short*)(ws + U + U / 4); // 0.5U
  unsigned short* hid16  = (unsigned short*)ws;               // [0, 2U) after msda
  unsigned short* emb2b  = (unsigned short*)(ws + 2 * U);     // 0.5U bf16
  unsigned short* emb16  = (unsigned short*)(ws + 2 * U + U / 2); // 0.5U bf16
  unsigned short* vb16   = (unsigned short*)(ws + 3 * U);         // 0.5U
  unsigned short* qb16   = (unsigned short*)(ws + 3 * U + U / 2); // 0.5U
  unsigned short* fb16   = (unsigned short*)(ws + 4 * U);         // 0.5U
  unsigned short* wbuf   = (unsigned short*)(ws + 4 * U + U / 2);

  unsigned short* Wvt    = wbuf;            // offsets match wconv_all
  unsigned short* Wofft  = wbuf + 65536;
  unsigned short* Wattnt = wbuf + 131072;
  unsigned short* Wot    = wbuf + 163840;
  unsigned short* W1t    = wbuf + 229376;
  unsigned short* W2t    = wbuf + 491520;

  wconv_all<<<(753664 + 255) / 256, 256, 0, stream>>>(Wv, Woff, Wattn, Wo, W1, W2, wbuf);

  ln1_kernel<<<M_TOT / 4, 256, 0, stream>>>(embed, pos, ln1w, ln1b, vb16, qb16, emb16);

  gemm_proj<<<(M_TOT / 128) * 5, 256, 0, stream>>>(
      vb16, qb16, Wvt, Wofft, Wattnt, bv, boff, battn, valb16, offb16, awb16);

  msda_kernel<<<M_TOT, 256, 0, stream>>>(valb16, offb16, awb16, refp, msdab);

  gemm_wo_ln2<<<M_TOT / 128, 512, 0, stream>>>(
      msdab, Wot, bo, emb16, ln2w, ln2b, emb2b, fb16);

  gemm_bf16<<<(M_TOT / 128) * 8, 256, 0, stream>>>(
      fb16, W1t, b1, nullptr, nullptr, nullptr, hid16, 256, 1024, 1, 8);
  gemm_bf16<<<(M_TOT / 128) * 2, 256, 0, stream>>>(
      hid16, W2t, b2, nullptr, emb2b, out, nullptr, 1024, 256, 0, 2);
}

// Round 17
// 284.088 us; speedup vs baseline: 1.0745x; 1.0285x over previous
//
#include <hip/hip_runtime.h>
#include <cstdint>
#include <cstddef>

#define N_TOTAL 21760
#define BATCH   2
#define M_TOT   (BATCH * N_TOTAL)   // 43520
#define DMODEL  256
#define NHEAD   8
#define HDIM    32
#define FFN     1024

typedef __bf16 b16x8 __attribute__((ext_vector_type(8)));
typedef float  f32x4 __attribute__((ext_vector_type(4)));
typedef float  f32x2 __attribute__((ext_vector_type(2)));

typedef const __attribute__((address_space(1))) void g_void;
typedef __attribute__((address_space(3))) void lds_void;

#if defined(__has_builtin)
#if __has_builtin(__builtin_amdgcn_make_buffer_rsrc) && __has_builtin(__builtin_amdgcn_raw_buffer_load_b32)
#define MSDA_BUFLD 1
#endif
#endif

// fp32 -> bf16 RNE
__device__ __forceinline__ unsigned short f2b(float f) {
  union { float f; unsigned u; } v; v.f = f;
  unsigned r = v.u + 0x7FFF + ((v.u >> 16) & 1);
  return (unsigned short)(r >> 16);
}
__device__ __forceinline__ float b2f(unsigned short u) {
  union { unsigned u; float f; } v; v.u = (unsigned)u << 16;
  return v.f;
}

// bijective XCD de-swizzle (m204)
__device__ __forceinline__ int xcd_wgid(int bid, int nwg) {
  int q = nwg >> 3, r = nwg & 7;
  int xcd = bid & 7, k = bid >> 3;
  return (xcd < r ? xcd * (q + 1) : r * (q + 1) + (xcd - r) * q) + k;
}

// ---------------------------------------------- weight convert + transpose
// ranges: Wv [0,65536) Woff [65536,131072) Wattn [131072,163840)
//         Wo [163840,229376) W1 [229376,491520) W2 [491520,753664)
__global__ void wconv_all(const float* __restrict__ Wv, const float* __restrict__ Woff,
                          const float* __restrict__ Wattn, const float* __restrict__ Wo,
                          const float* __restrict__ W1, const float* __restrict__ W2,
                          unsigned short* __restrict__ dstbase) {
  int idx = blockIdx.x * 256 + threadIdx.x;  // 0 .. 753664
  const float* src; int K, N, off;
  if (idx < 65536)       { src = Wv;    K = 256;  N = 256;  off = 0;      }
  else if (idx < 131072) { src = Woff;  K = 256;  N = 256;  off = 65536;  idx -= 65536; }
  else if (idx < 163840) { src = Wattn; K = 256;  N = 128;  off = 131072; idx -= 131072; }
  else if (idx < 229376) { src = Wo;    K = 256;  N = 256;  off = 163840; idx -= 163840; }
  else if (idx < 491520) { src = W1;    K = 256;  N = 1024; off = 229376; idx -= 229376; }
  else if (idx < 753664) { src = W2;    K = 1024; N = 256;  off = 491520; idx -= 491520; }
  else return;
  int k = idx / N, n = idx - k * N;
  dstbase[off + (size_t)n * K + k] = f2b(src[idx]);
}

// ---------------------------------------------------------------- LayerNorm
__global__ void ln1_kernel(const float* __restrict__ x, const float* __restrict__ pos,
                           const float* __restrict__ w, const float* __restrict__ b,
                           unsigned short* __restrict__ vb, unsigned short* __restrict__ qb) {
  int t = threadIdx.x;
  int tkn = blockIdx.x * 4 + (t >> 6);
  int lane = t & 63;
  size_t base = (size_t)tkn * DMODEL + lane * 4;
  float4 xv = *(const float4*)&x[base];
  float s1 = xv.x + xv.y + xv.z + xv.w;
  float s2 = xv.x * xv.x + xv.y * xv.y + xv.z * xv.z + xv.w * xv.w;
  #pragma unroll
  for (int off = 32; off; off >>= 1) {
    s1 += __shfl_down(s1, off);
    s2 += __shfl_down(s2, off);
  }
  s1 = __shfl(s1, 0); s2 = __shfl(s2, 0);
  float m   = s1 * (1.0f / DMODEL);
  float var = s2 * (1.0f / DMODEL) - m * m;
  float rs  = rsqrtf(var + 1e-5f);
  float4 wv = *(const float4*)&w[lane * 4];
  float4 bv = *(const float4*)&b[lane * 4];
  float4 pv = *(const float4*)&pos[base];
  float o0 = (xv.x - m) * rs * wv.x + bv.x;
  float o1 = (xv.y - m) * rs * wv.y + bv.y;
  float o2 = (xv.z - m) * rs * wv.z + bv.z;
  float o3 = (xv.w - m) * rs * wv.w + bv.w;
  ushort4 vo = {f2b(o0), f2b(o1), f2b(o2), f2b(o3)};
  ushort4 qo = {f2b(o0 + pv.x), f2b(o1 + pv.y), f2b(o2 + pv.z), f2b(o3 + pv.w)};
  *(ushort4*)&vb[base] = vo;
  *(ushort4*)&qb[base] = qo;
}

// ------------------------------------------------------- bf16 MFMA GEMM core
// R10 structure (measured best): 1-phase m97 staging + T2 swizzle both-sides;
// bf16 output via LDS repack -> 256B stores. 32 KB LDS, 3 blocks/CU.
__device__ __forceinline__ void gemm_core(
    const unsigned short* __restrict__ A, const unsigned short* __restrict__ Bt,
    const float* __restrict__ bias,
    const float* __restrict__ addf, const unsigned short* __restrict__ addb,
    float* __restrict__ Cf, unsigned short* __restrict__ Cb,
    int K, int N, int relu, int row0, int col0,
    unsigned short* S /* 16384 shorts: As=S, Bs=S+8192 */) {
  unsigned short* As = S;
  unsigned short* Bs = S + 8192;
  int t  = threadIdx.x;
  int w  = t >> 6;
  int l  = t & 63;
  int wm = w >> 1, wn = w & 1;
  int lr = l & 15;
  int kq = l >> 4;

  f32x4 acc[4][4];
  #pragma unroll
  for (int i = 0; i < 4; ++i)
    #pragma unroll
    for (int j = 0; j < 4; ++j) acc[i][j] = (f32x4){0.f, 0.f, 0.f, 0.f};

  int srow = l >> 3;                      // row within 8-row chunk
  int swseg = ((l & 7) ^ srow) * 8;       // swizzled 16B granule (elements)

  for (int k0 = 0; k0 < K; k0 += 64) {
    #pragma unroll
    for (int i = 0; i < 4; ++i) {
      int c = w * 4 + i;
      const unsigned short* ga = A  + (size_t)(row0 + c * 8 + srow) * K + k0 + swseg;
      const unsigned short* gb = Bt + (size_t)(col0 + c * 8 + srow) * K + k0 + swseg;
      __builtin_amdgcn_global_load_lds((g_void*)ga, (lds_void*)(As + c * 512), 16, 0, 0);
      __builtin_amdgcn_global_load_lds((g_void*)gb, (lds_void*)(Bs + c * 512), 16, 0, 0);
    }
    __syncthreads();
    #pragma unroll
    for (int kk = 0; kk < 2; ++kk) {
      b16x8 aF[4], bF[4];
      #pragma unroll
      for (int i = 0; i < 4; ++i) {
        int row = wm * 64 + i * 16 + lr;
        int gp = (kk * 4 + kq) ^ (lr & 7);
        aF[i] = *(const b16x8*)&As[row * 64 + gp * 8];
      }
      #pragma unroll
      for (int j = 0; j < 4; ++j) {
        int row = wn * 64 + j * 16 + lr;
        int gp = (kk * 4 + kq) ^ (lr & 7);
        bF[j] = *(const b16x8*)&Bs[row * 64 + gp * 8];
      }
      #pragma unroll
      for (int i = 0; i < 4; ++i)
        #pragma unroll
        for (int j = 0; j < 4; ++j)
          acc[i][j] = __builtin_amdgcn_mfma_f32_16x16x32_bf16(aF[i], bF[j], acc[i][j], 0, 0, 0);
    }
    __syncthreads();
  }

  if (Cb) {
    // deposit into [128][128] repack buffer (col XOR'd by row&3 to spread banks)
    #pragma unroll
    for (int j = 0; j < 4; ++j) {
      int coll = wn * 64 + j * 16 + lr;
      int colg = col0 + coll;
      float bcol = bias[colg];
      #pragma unroll
      for (int i = 0; i < 4; ++i) {
        int rl0 = wm * 64 + i * 16 + kq * 4;
        #pragma unroll
        for (int r = 0; r < 4; ++r) {
          int rowl = rl0 + r;
          float o = acc[i][j][r] + bcol;
          if (relu) o = fmaxf(o, 0.0f);
          if (addf) o += addf[(size_t)(row0 + rowl) * N + colg];
          if (addb) o += b2f(addb[(size_t)(row0 + rowl) * N + colg]);
          S[rowl * 128 + (coll ^ ((rowl & 3) << 5))] = f2b(o);
        }
      }
    }
    __syncthreads();
    #pragma unroll
    for (int m = 0; m < 8; ++m) {
      int cc = m * 256 + t;
      int row = cc >> 4, g = cc & 15;
      float4 v = *(const float4*)&S[row * 128 + ((g ^ ((row & 3) << 2)) << 3)];
      *(float4*)&Cb[(size_t)(row0 + row) * N + col0 + g * 8] = v;
    }
  } else {
    #pragma unroll
    for (int j = 0; j < 4; ++j) {
      int colg = col0 + wn * 64 + j * 16 + lr;
      float bcol = bias[colg];
      #pragma unroll
      for (int i = 0; i < 4; ++i) {
        int r0g = row0 + wm * 64 + i * 16 + kq * 4;
        #pragma unroll
        for (int r = 0; r < 4; ++r) {
          int rowg = r0g + r;
          float o = acc[i][j][r] + bcol;
          if (relu) o = fmaxf(o, 0.0f);
          if (addf) o += addf[(size_t)rowg * N + colg];
          if (addb) o += b2f(addb[(size_t)rowg * N + colg]);
          Cf[(size_t)rowg * N + colg] = o;
        }
      }
    }
  }
}

// flat 1-D grid; XCD-chunked, column-tile fastest within a chunk
__global__ __launch_bounds__(256, 3)
void gemm_bf16(const unsigned short* __restrict__ A,
               const unsigned short* __restrict__ Bt,
               const float* __restrict__ bias,
               const float* __restrict__ addf, const unsigned short* __restrict__ addb,
               float* __restrict__ Cf, unsigned short* __restrict__ Cb,
               int K, int N, int relu, int ncolt) {
  __shared__ unsigned short S[16384];
  int wgid = xcd_wgid(blockIdx.x, gridDim.x);
  int row0 = (wgid / ncolt) * 128;
  int col0 = (wgid % ncolt) * 128;
  gemm_core(A, Bt, bias, addf, addb, Cf, Cb, K, N, relu, row0, col0, S);
}

// fused projections: sub-gemm y 0,1 -> value; 2,3 -> offsets; 4 -> attn logits
__global__ __launch_bounds__(256, 3)
void gemm_proj(const unsigned short* __restrict__ vb,
               const unsigned short* __restrict__ qb,
               const unsigned short* __restrict__ Wvt,
               const unsigned short* __restrict__ Wofft,
               const unsigned short* __restrict__ Wattnt,
               const float* __restrict__ bv, const float* __restrict__ boff,
               const float* __restrict__ battn,
               unsigned short* __restrict__ valb,
               unsigned short* __restrict__ offb,
               unsigned short* __restrict__ awb) {
  __shared__ unsigned short S[16384];
  int wgid = xcd_wgid(blockIdx.x, gridDim.x);
  int y = wgid % 5;              // y fastest -> A-panel reuse within XCD chunk
  int row0 = (wgid / 5) * 128;
  const unsigned short* A; const unsigned short* Bt; const float* bias;
  unsigned short* C; int col0, N;
  if (y < 2)      { A = vb; Bt = Wvt;    bias = bv;    C = valb; col0 = y * 128;       N = 256; }
  else if (y < 4) { A = qb; Bt = Wofft;  bias = boff;  C = offb; col0 = (y - 2) * 128; N = 256; }
  else            { A = qb; Bt = Wattnt; bias = battn; C = awb;  col0 = 0;             N = 128; }
  gemm_core(A, Bt, bias, nullptr, nullptr, nullptr, C, 256, N, 0, row0, col0, S);
}

// --------------------------------- Wo GEMM (128x256 tile) + fused LN2 epilogue
__global__ __launch_bounds__(512, 2)
void gemm_wo_ln2(const unsigned short* __restrict__ A,   // msdab
                 const unsigned short* __restrict__ Bt,  // Wot [256][256]
                 const float* __restrict__ bias,         // bo
                 const float* __restrict__ emb,          // embed fp32
                 const float* __restrict__ lnw, const float* __restrict__ lnb,
                 unsigned short* __restrict__ emb2b,
                 unsigned short* __restrict__ fb16) {
  __shared__ unsigned short S[24576];   // As 8192 + Bs 16384 (48 KB)
  __shared__ float lnS1[128 * 4], lnS2[128 * 4];
  __shared__ float lnM[128], lnR[128];
  unsigned short* As = S;
  unsigned short* Bs = S + 8192;
  int t  = threadIdx.x;
  int w  = t >> 6;
  int l  = t & 63;
  int wm = w >> 2, wn = w & 3;
  int lr = l & 15;
  int kq = l >> 4;
  int row0 = xcd_wgid(blockIdx.x, gridDim.x) * 128;

  f32x4 acc[4][4];
  #pragma unroll
  for (int i = 0; i < 4; ++i)
    #pragma unroll
    for (int j = 0; j < 4; ++j) acc[i][j] = (f32x4){0.f, 0.f, 0.f, 0.f};

  int srow = l >> 3;
  int swseg = ((l & 7) ^ srow) * 8;

  for (int k0 = 0; k0 < 256; k0 += 64) {
    #pragma unroll
    for (int i = 0; i < 2; ++i) {
      int c = w * 2 + i;
      const unsigned short* ga = A + (size_t)(row0 + c * 8 + srow) * 256 + k0 + swseg;
      __builtin_amdgcn_global_load_lds((g_void*)ga, (lds_void*)(As + c * 512), 16, 0, 0);
    }
    #pragma unroll
    for (int i = 0; i < 4; ++i) {
      int c = w * 4 + i;
      const unsigned short* gb = Bt + (size_t)(c * 8 + srow) * 256 + k0 + swseg;
      __builtin_amdgcn_global_load_lds((g_void*)gb, (lds_void*)(Bs + c * 512), 16, 0, 0);
    }
    __syncthreads();
    #pragma unroll
    for (int kk = 0; kk < 2; ++kk) {
      b16x8 aF[4], bF[4];
      #pragma unroll
      for (int i = 0; i < 4; ++i) {
        int row = wm * 64 + i * 16 + lr;
        int gp = (kk * 4 + kq) ^ (lr & 7);
        aF[i] = *(const b16x8*)&As[row * 64 + gp * 8];
      }
      #pragma unroll
      for (int j = 0; j < 4; ++j) {
        int row = wn * 64 + j * 16 + lr;
        int gp = (kk * 4 + kq) ^ (lr & 7);
        bF[j] = *(const b16x8*)&Bs[row * 64 + gp * 8];
      }
      #pragma unroll
      for (int i = 0; i < 4; ++i)
        #pragma unroll
        for (int j = 0; j < 4; ++j)
          acc[i][j] = __builtin_amdgcn_mfma_f32_16x16x32_bf16(aF[i], bF[j], acc[i][j], 0, 0, 0);
    }
    __syncthreads();
  }

  // pass 1: o = acc + bias + embed; partial row sums
  float s1[4][4] = {}, s2[4][4] = {};
  #pragma unroll
  for (int j = 0; j < 4; ++j) {
    int colg = wn * 64 + j * 16 + lr;
    float bcol = bias[colg];
    #pragma unroll
    for (int i = 0; i < 4; ++i) {
      int rowg = row0 + wm * 64 + i * 16 + kq * 4;
      #pragma unroll
      for (int r = 0; r < 4; ++r) {
        float o = acc[i][j][r] + bcol + emb[(size_t)(rowg + r) * 256 + colg];
        acc[i][j][r] = o;
        s1[i][r] += o;
        s2[i][r] += o * o;
      }
    }
  }
  #pragma unroll
  for (int m = 1; m < 16; m <<= 1) {
    #pragma unroll
    for (int i = 0; i < 4; ++i)
      #pragma unroll
      for (int r = 0; r < 4; ++r) {
        s1[i][r] += __shfl_xor(s1[i][r], m);
        s2[i][r] += __shfl_xor(s2[i][r], m);
      }
  }
  if (lr == 0) {
    #pragma unroll
    for (int i = 0; i < 4; ++i)
      #pragma unroll
      for (int r = 0; r < 4; ++r) {
        int rl = wm * 64 + i * 16 + kq * 4 + r;
        lnS1[rl * 4 + wn] = s1[i][r];
        lnS2[rl * 4 + wn] = s2[i][r];
      }
  }
  __syncthreads();
  if (t < 128) {
    float a = lnS1[t * 4] + lnS1[t * 4 + 1] + lnS1[t * 4 + 2] + lnS1[t * 4 + 3];
    float b = lnS2[t * 4] + lnS2[t * 4 + 1] + lnS2[t * 4 + 2] + lnS2[t * 4 + 3];
    float m = a * (1.0f / 256.0f);
    float var = b * (1.0f / 256.0f) - m * m;
    lnM[t] = m;
    lnR[t] = rsqrtf(var + 1e-5f);
  }
  __syncthreads();

  // repack passes: out 0 = emb2b (o), out 1 = fb16 (LN2(o)); halves of 128 cols
  #pragma unroll
  for (int outn = 0; outn < 2; ++outn) {
    unsigned short* dst = outn == 0 ? emb2b : fb16;
    #pragma unroll
    for (int half = 0; half < 2; ++half) {
      __syncthreads();
      if ((wn >> 1) == half) {
        #pragma unroll
        for (int j = 0; j < 4; ++j) {
          int colg = wn * 64 + j * 16 + lr;
          int coll = colg - half * 128;
          #pragma unroll
          for (int i = 0; i < 4; ++i) {
            #pragma unroll
            for (int r = 0; r < 4; ++r) {
              int rowl = wm * 64 + i * 16 + kq * 4 + r;
              float o = acc[i][j][r];
              float vv = outn == 0 ? o
                  : (o - lnM[rowl]) * lnR[rowl] * lnw[colg] + lnb[colg];
              S[rowl * 128 + (coll ^ ((rowl & 3) << 5))] = f2b(vv);
            }
          }
        }
      }
      __syncthreads();
      #pragma unroll
      for (int m = 0; m < 4; ++m) {
        int cc = m * 512 + t;
        int row = cc >> 4, g = cc & 15;
        float4 v = *(const float4*)&S[row * 128 + ((g ^ ((row & 3) << 2)) << 3)];
        *(float4*)&dst[(size_t)(row0 + row) * 256 + half * 128 + g * 8] = v;
      }
    }
  }
}

// --------------------------------------------------- MSDA sampling + softmax
// R13-exact phase 2 (measured best): single int2 P read, buffer load, pk_fma.
__global__ void msda_kernel(const unsigned short* __restrict__ value,
                            const unsigned short* __restrict__ offb,
                            const unsigned short* __restrict__ awb,
                            const float* __restrict__ ref,
                            unsigned short* __restrict__ outb) {
  __shared__ int2 P[544];   // 8 heads * 68, half stride 34
  int bid = blockIdx.x;
  int tkn = (bid & 7) * (M_TOT / 8) + (bid >> 3);
  int t   = threadIdx.x;
  int b   = (tkn >= N_TOTAL) ? 1 : 0;

  if (t < 128) {
    int h = t >> 4, s = t & 15, lev = s >> 2, p = s & 3;
    float lg = b2f(awb[(size_t)tkn * 128 + h * 16 + s]);
    float mx = lg;
    #pragma unroll
    for (int m = 1; m < 16; m <<= 1) mx = fmaxf(mx, __shfl_xor(mx, m, 16));
    float e = __expf(lg - mx);
    float sum = e;
    #pragma unroll
    for (int m = 1; m < 16; m <<= 1) sum += __shfl_xor(sum, m, 16);
    float aw = e / sum;

    const int HL[4] = {128, 64, 32, 16};
    const int ST[4] = {0, 16384, 20480, 21504};
    int Wl = HL[lev];
    float rx = ref[(size_t)tkn * 8 + lev * 2 + 0];
    float ry = ref[(size_t)tkn * 8 + lev * 2 + 1];
    float ox = b2f(offb[(size_t)tkn * 256 + h * 32 + lev * 8 + p * 2 + 0]);
    float oy = b2f(offb[(size_t)tkn * 256 + h * 32 + lev * 8 + p * 2 + 1]);
    float x = rx * (float)Wl + ox - 0.5f;   // Hl == Wl all levels
    float y = ry * (float)Wl + oy - 0.5f;
    float x0f = floorf(x), y0f = floorf(y);
    float wx = x - x0f, wy = y - y0f;
    int x0 = (int)x0f, y0 = (int)y0f;
    float wt[4] = {(1.f - wx) * (1.f - wy), wx * (1.f - wy),
                   (1.f - wx) * wy, wx * wy};
    int base = b * N_TOTAL + ST[lev];
    #pragma unroll
    for (int tp = 0; tp < 4; ++tp) {
      int e4 = s * 4 + tp;                       // 0..63 within head
      int idx = h * 68 + (e4 >> 5) * 34 + (e4 & 31);
      int xi = x0 + (tp & 1), yi = y0 + (tp >> 1);
      bool ok = (xi >= 0) & (xi < Wl) & (yi >= 0) & (yi < Wl);
      float wgt = ok ? aw * wt[tp] : 0.f;
      int boff2 = ok ? (((base + yi * Wl + xi) * 256 + h * 32) * 2) : 0;
      P[idx] = (int2){__float_as_int(wgt), boff2};
    }
  }
  __syncthreads();

  int h = t >> 5, g = t & 31, dp = g & 15, half = g >> 4;
  int o = h * 68 + half * 34;
  unsigned doff = dp * 4;  // byte offset of d-pair within 64B head segment
#ifdef MSDA_BUFLD
  __amdgpu_buffer_rsrc_t rsrc = __builtin_amdgcn_make_buffer_rsrc(
      (void*)value, (short)0, (int)(M_TOT * 512), 0x00020000);
#else
  const char* vbase = (const char*)value;
#endif
  f32x2 acc = {0.f, 0.f};
  #pragma unroll 16
  for (int j = 0; j < 32; ++j) {
    int2 pr = P[o + j];
    float wgt = __int_as_float(pr.x);
#ifdef MSDA_BUFLD
    unsigned v = __builtin_amdgcn_raw_buffer_load_b32(
        rsrc, (int)((unsigned)pr.y + doff), 0, 0);
#else
    unsigned v = *(const unsigned*)(vbase + (size_t)((unsigned)pr.y + doff));
#endif
    union { unsigned u; float f; } lo, hi;
    lo.u = v << 16;
    hi.u = v;                         // junk low mantissa: < 1 bf16 ulp
    f32x2 vv = {lo.f, hi.f};
    f32x2 w2 = {wgt, wgt};
    acc += w2 * vv;                   // v_pk_fma_f32
  }
  acc.x += __shfl_xor(acc.x, 16);
  acc.y += __shfl_xor(acc.y, 16);
  if (half == 0) {
    unsigned pk = (unsigned)f2b(acc.x) | ((unsigned)f2b(acc.y) << 16);
    *(unsigned*)&outb[(size_t)tkn * 256 + h * 32 + dp * 2] = pk;
  }
}

// --------------------------------------------------------------- launcher
extern "C" void kernel_launch(void* const* d_in, const int* in_sizes, int n_in,
                              void* d_out, int out_size, void* d_ws, size_t ws_size,
                              hipStream_t stream) {
  const float* embed = (const float*)d_in[0];
  const float* pos   = (const float*)d_in[1];
  const float* refp  = (const float*)d_in[2];
  const float* ln1w  = (const float*)d_in[3];
  const float* ln1b  = (const float*)d_in[4];
  const float* ln2w  = (const float*)d_in[5];
  const float* ln2b  = (const float*)d_in[6];
  const float* Wv    = (const float*)d_in[7];
  const float* bv    = (const float*)d_in[8];
  const float* Woff  = (const float*)d_in[9];
  const float* boff  = (const float*)d_in[10];
  const float* Wattn = (const float*)d_in[11];
  const float* battn = (const float*)d_in[12];
  const float* Wo    = (const float*)d_in[13];
  const float* bo    = (const float*)d_in[14];
  const float* W1    = (const float*)d_in[15];
  const float* b1    = (const float*)d_in[16];
  const float* W2    = (const float*)d_in[17];
  const float* b2    = (const float*)d_in[18];
  float* out = (float*)d_out;
  float* ws  = (float*)d_ws;

  const size_t U = (size_t)M_TOT * DMODEL;  // 11,141,120 floats
  unsigned short* valb16 = (unsigned short*)ws;               // 0.5U floats
  unsigned short* offb16 = (unsigned short*)(ws + U / 2);     // 0.5U
  unsigned short* awb16  = (unsigned short*)(ws + U);         // 0.25U
  unsigned short* msdab  = (unsigned short*)(ws + U + U / 4); // 0.5U
  unsigned short* hid16  = (unsigned short*)ws;               // [0, 2U) after msda
  unsigned short* emb2b  = (unsigned short*)(ws + 2 * U);     // 0.5U bf16
  unsigned short* vb16   = (unsigned short*)(ws + 3 * U);         // 0.5U
  unsigned short* qb16   = (unsigned short*)(ws + 3 * U + U / 2); // 0.5U
  unsigned short* fb16   = (unsigned short*)(ws + 4 * U);         // 0.5U
  unsigned short* wbuf   = (unsigned short*)(ws + 4 * U + U / 2);

  unsigned short* Wvt    = wbuf;            // offsets match wconv_all
  unsigned short* Wofft  = wbuf + 65536;
  unsigned short* Wattnt = wbuf + 131072;
  unsigned short* Wot    = wbuf + 163840;
  unsigned short* W1t    = wbuf + 229376;
  unsigned short* W2t    = wbuf + 491520;

  wconv_all<<<(753664 + 255) / 256, 256, 0, stream>>>(Wv, Woff, Wattn, Wo, W1, W2, wbuf);

  ln1_kernel<<<M_TOT / 4, 256, 0, stream>>>(embed, pos, ln1w, ln1b, vb16, qb16);

  gemm_proj<<<(M_TOT / 128) * 5, 256, 0, stream>>>(
      vb16, qb16, Wvt, Wofft, Wattnt, bv, boff, battn, valb16, offb16, awb16);

  msda_kernel<<<M_TOT, 256, 0, stream>>>(valb16, offb16, awb16, refp, msdab);

  gemm_wo_ln2<<<M_TOT / 128, 512, 0, stream>>>(
      msdab, Wot, bo, embed, ln2w, ln2b, emb2b, fb16);

  gemm_bf16<<<(M_TOT / 128) * 8, 256, 0, stream>>>(
      fb16, W1t, b1, nullptr, nullptr, nullptr, hid16, 256, 1024, 1, 8);
  gemm_bf16<<<(M_TOT / 128) * 2, 256, 0, stream>>>(
      hid16, W2t, b2, nullptr, emb2b, out, nullptr, 1024, 256, 0, 2);
}